// Round 9
// baseline (178.524 us; speedup 1.0000x reference)
//
#include <hip/hip_runtime.h>

// Luong attention, flash-style, f16 MFMA. V streamed from L2 (no V LDS).
// enc [B,Te,D] f32, dec [B,Td,D] f32 -> out [B,Td,2D] f32 (concat(dec, context))
// Prepass: encK f16 (row-major, 16B-chunk swizzle x^=e&7 within 64d group)
//          encVt f16 [b][ct=e/32][d][32] interleaved: chunk gpos holds
//          {e=ct*32+4*gpos..+3, e=ct*32+16+4*gpos..+3}  (NO xor swizzle)
// Main: 512 thr = 2 e-groups x 4 t-waves x 16 q-rows. KBLK=32.
//   K 2-deep LDS (64 KB); V -> registers from L2 (batch-per-XCD => L2-hot).
//   iter: Vload(it) -> QK(slot) -> in-lane SM -> PV(16x16x16) -> barrier
//         -> KSTAGE(it+2 -> slot). One barrier/iter; drains provably free.

#define B_   8
#define TE   2048
#define TD   2048
#define D_   256
#define NIT  32   // (TE/2)/32 k-tiles per e-group

typedef _Float16 f16x8 __attribute__((ext_vector_type(8)));
typedef _Float16 f16x4 __attribute__((ext_vector_type(4)));
typedef float f32x4 __attribute__((ext_vector_type(4)));

#define GLOAD16(gsrc, ldst)                                                  \
  __builtin_amdgcn_global_load_lds(                                          \
      (const __attribute__((address_space(1))) unsigned int*)(const void*)(gsrc), \
      (__attribute__((address_space(3))) unsigned int*)(void*)(ldst), 16, 0, 0)

// ---- fused prepass: one 64e x 64d f32 tile -> encK chunk + encVt chunk ----
__global__ __launch_bounds__(256) void prep_fused(const float* __restrict__ enc,
                                                  _Float16* __restrict__ encK,
                                                  _Float16* __restrict__ encVt) {
  __shared__ float tile[64][65];
  int bid = blockIdx.x;                 // 8 b * 32 et * 4 dt = 1024
  int b = bid >> 7, r = bid & 127;
  int et = r >> 2, dt = r & 3;
  int e0 = et * 64, d0 = dt * 64;
  int tx = threadIdx.x & 63, ty = threadIdx.x >> 6;
  const float* src = enc + ((size_t)b * TE + e0) * D_ + d0;
#pragma unroll
  for (int i = 0; i < 16; ++i)
    tile[i * 4 + ty][tx] = src[(size_t)(i * 4 + ty) * D_ + tx];
  __syncthreads();

  // encK: chunk xl of row e holds source chunk xl^(e&7) (within this 64d group)
  _Float16* kout = encK + ((size_t)b * TE + e0) * D_ + d0;
#pragma unroll
  for (int i = 0; i < 2; ++i) {
    int ci = i * 256 + threadIdx.x;     // 0..511
    int e = ci >> 3, xl = ci & 7;
    int xs = xl ^ (e & 7);
    const float* s8 = &tile[e][xs * 8];
    f16x8 h;
#pragma unroll
    for (int j = 0; j < 8; ++j) h[j] = (_Float16)s8[j];
    *(f16x8*)(kout + (size_t)e * D_ + xl * 8) = h;
  }
  // encVt: per (ct, d): chunk gpos holds {e=ct*32+4*gpos..+3, +16..+19}
#pragma unroll
  for (int i = 0; i < 2; ++i) {
    int u = i * 256 + threadIdx.x;      // 0..511
    int gpos = u & 3, d_loc = (u >> 2) & 63, ctl = u >> 8;
    int eb = ctl * 32 + 4 * gpos;
    f16x8 h;
#pragma unroll
    for (int j = 0; j < 4; ++j) h[j] = (_Float16)tile[eb + j][d_loc];
#pragma unroll
    for (int j = 0; j < 4; ++j) h[4 + j] = (_Float16)tile[eb + 16 + j][d_loc];
    size_t o = (((size_t)b * 64 + et * 2 + ctl) * 256 + d0 + d_loc) * 32 + gpos * 8;
    *(f16x8*)(encVt + o) = h;
  }
}

__global__ __launch_bounds__(512, 2) void luong_main(
    const _Float16* __restrict__ encK,   // [B][TE][256] swizzled
    const _Float16* __restrict__ encVt,  // [B][64][256][32] interleaved
    const float* __restrict__ dec,
    float* __restrict__ out) {
  extern __shared__ char lds[];
  const int tid = threadIdx.x;
  const int lane = tid & 63, wave = tid >> 6;     // 8 waves
  const int wr = wave >> 2, tw = wave & 3;        // e-group, t-wave
  const int g = lane >> 4, c = lane & 15;

  int bidl = (blockIdx.x & 7) * 32 + (blockIdx.x >> 3);  // batch k -> XCD k
  const int b = bidl >> 5;
  const int q0 = (bidl & 31) * 64;
  const int tbase = q0 + tw * 16;                 // this wave's 16 q-cols

  const float* decB = dec + (size_t)b * TD * D_;
  float* outB = out + (size_t)b * TD * (2 * D_);

  const _Float16* kbase = encK + ((size_t)b * TE + wr * 1024) * D_;
  const _Float16* vbase = encVt + ((size_t)b * 64 + wr * 32) * 8192;

  char* grpK = lds + (size_t)wr * 32768;          // 2 slots x 16 KiB

  auto KSTAGE = [&](int slot, int it) {
    char* Kd = grpK + slot * 16384 + tw * 4096;
    const _Float16* ks = kbase + (size_t)it * 8192 + tw * 2048;
#pragma unroll
    for (int q = 0; q < 4; ++q)
      GLOAD16(ks + q * 512 + lane * 8, Kd + q * 1024 + lane * 16);
  };

  // ---- prologue stages: K0, K1 ----
  KSTAGE(0, 0); KSTAGE(1, 1);

  // dec -> out[:, :256] copy (overlaps staging flight)
#pragma unroll
  for (int i = 0; i < 8; ++i) {
    int ci = tid + 512 * i;
    int rr = ci >> 6, d4 = (ci & 63) << 2;
    *(float4*)(outB + (size_t)(q0 + rr) * 512 + d4) =
        *(const float4*)(decB + (size_t)(q0 + rr) * 256 + d4);
  }

  // ---- Q fragments f16 hi/lo (16 rows) ----
  f16x8 qh[8], ql[8];
  {
    const float* qrow = decB + (size_t)(tbase + c) * D_;
#pragma unroll
    for (int dc = 0; dc < 8; ++dc) {
      float4 v0 = *(const float4*)(qrow + dc * 32 + 8 * g);
      float4 v1 = *(const float4*)(qrow + dc * 32 + 8 * g + 4);
      float f[8] = {v0.x, v0.y, v0.z, v0.w, v1.x, v1.y, v1.z, v1.w};
      f16x8 H, L;
#pragma unroll
      for (int j = 0; j < 8; ++j) {
        _Float16 h = (_Float16)f[j];
        H[j] = h;
        L[j] = (_Float16)(f[j] - (float)h);
      }
      qh[dc] = H; ql[dc] = L;
    }
  }

  __syncthreads();   // prologue drain: K0,K1 landed, visible to all waves

  float m_run = -INFINITY, l_run = 0.f;
  f32x4 ctx[16];
#pragma unroll
  for (int i = 0; i < 16; ++i) ctx[i] = (f32x4){0.f, 0.f, 0.f, 0.f};

  for (int it = 0; it < NIT; ++it) {
    const int slot = it & 1;
    const char* Kb = grpK + slot * 16384;

    // ---- V prefetch (L2-hot): consumed ~QK+SM later ----
    f16x8 vreg[16];
    const _Float16* vt = vbase + (size_t)it * 8192;
#pragma unroll
    for (int dt = 0; dt < 16; ++dt)
      vreg[dt] = *(const f16x8*)(vt + (dt * 16 + c) * 32 + g * 8);

    // ---- QK (swapped): sA = S[e=4g+r][c], sB = S[e=16+4g+r][c] ----
    f32x4 sA = (f32x4){0.f, 0.f, 0.f, 0.f};
    f32x4 sB = (f32x4){0.f, 0.f, 0.f, 0.f};
#pragma unroll
    for (int dc = 0; dc < 8; ++dc) {
      int x = dc * 4 + g;
      int xsw = (x & 24) | ((x ^ c) & 7);   // (16+c)&7 == c&7
      f16x8 k0 = *(const f16x8*)(Kb + c * 512 + (xsw << 4));
      f16x8 k1 = *(const f16x8*)(Kb + (16 + c) * 512 + (xsw << 4));
      sA = __builtin_amdgcn_mfma_f32_16x16x32_f16(k0, qh[dc], sA, 0, 0, 0);
      sA = __builtin_amdgcn_mfma_f32_16x16x32_f16(k0, ql[dc], sA, 0, 0, 0);
      sB = __builtin_amdgcn_mfma_f32_16x16x32_f16(k1, qh[dc], sB, 0, 0, 0);
      sB = __builtin_amdgcn_mfma_f32_16x16x32_f16(k1, ql[dc], sB, 0, 0, 0);
    }

    // ---- in-lane softmax -> f16x4 B-fragments (no shuffles for P) ----
    f16x4 bfA, bfB;
    {
      float vmax = fmaxf(fmaxf(fmaxf(sA[0], sA[1]), fmaxf(sA[2], sA[3])),
                         fmaxf(fmaxf(sB[0], sB[1]), fmaxf(sB[2], sB[3])));
      vmax = fmaxf(vmax, __shfl_xor(vmax, 16, 64));
      vmax = fmaxf(vmax, __shfl_xor(vmax, 32, 64));
      if (!__all(vmax <= m_run + 8.0f)) {     // T13 defer-max
        float mn = fmaxf(m_run, vmax);
        float alpha = __expf(m_run - mn);
        l_run *= alpha;
#pragma unroll
        for (int i = 0; i < 16; ++i) ctx[i] *= alpha;
        m_run = mn;
      }
      float p0 = __expf(sA[0] - m_run), p1 = __expf(sA[1] - m_run);
      float p2 = __expf(sA[2] - m_run), p3 = __expf(sA[3] - m_run);
      float p4 = __expf(sB[0] - m_run), p5 = __expf(sB[1] - m_run);
      float p6 = __expf(sB[2] - m_run), p7 = __expf(sB[3] - m_run);
      float ps = ((p0 + p1) + (p2 + p3)) + ((p4 + p5) + (p6 + p7));
      ps += __shfl_xor(ps, 16, 64);
      ps += __shfl_xor(ps, 32, 64);
      l_run += ps;
      bfA[0] = (_Float16)p0; bfA[1] = (_Float16)p1;
      bfA[2] = (_Float16)p2; bfA[3] = (_Float16)p3;
      bfB[0] = (_Float16)p4; bfB[1] = (_Float16)p5;
      bfB[2] = (_Float16)p6; bfB[3] = (_Float16)p7;
    }

    // ---- PV: 16x16x16, A = Vt fragments from registers ----
#pragma unroll
    for (int dt = 0; dt < 16; ++dt) {
      int4 vi = __builtin_bit_cast(int4, vreg[dt]);
      f16x4 a0 = __builtin_bit_cast(f16x4, make_int2(vi.x, vi.y));  // e 4g..4g+3
      f16x4 a1 = __builtin_bit_cast(f16x4, make_int2(vi.z, vi.w));  // e 16+4g..+3
      ctx[dt] = __builtin_amdgcn_mfma_f32_16x16x16f16(a0, bfA, ctx[dt], 0, 0, 0);
      ctx[dt] = __builtin_amdgcn_mfma_f32_16x16x16f16(a1, bfB, ctx[dt], 0, 0, 0);
    }

    // barrier: all reads of slot done; outstanding vmem already drained by
    // PV's register consumption (K(it+1) is older than V(it) in FIFO) ->
    // the implicit vmcnt(0) here is free.
    __syncthreads();
    if (it + 2 < NIT) KSTAGE(slot, it + 2);  // rides through next iteration
  }

  // ---- cross-group merge (2 e-groups, partner shares tw) ----
  float* mlb = (float*)(lds + 66560);
  if (g == 0) {
    mlb[(wave * 16 + c) * 2 + 0] = m_run;
    mlb[(wave * 16 + c) * 2 + 1] = l_run;
  }
  __syncthreads();
  int partner = (1 - wr) * 4 + tw;
  float mo = mlb[(partner * 16 + c) * 2 + 0];
  float lo = mlb[(partner * 16 + c) * 2 + 1];
  float M = fmaxf(m_run, mo);
  float fme = __expf(m_run - M);
  float L = l_run * fme + lo * __expf(mo - M);
  float invL = 1.0f / L;

  float* Xb = (float*)lds;   // [256 d][65 pad] f32, reuses K region (loop done)
  if (wr == 1) {
#pragma unroll
    for (int dt = 0; dt < 16; ++dt)
#pragma unroll
      for (int r = 0; r < 4; ++r) {
        int d = dt * 16 + 4 * g + r;
        Xb[d * 65 + tw * 16 + c] = ctx[dt][r] * fme;
      }
  }
  __syncthreads();
  if (wr == 0) {
    float* orow = outB + (size_t)(tbase + c) * 512 + 256;
#pragma unroll
    for (int dt = 0; dt < 16; ++dt) {
      float vv[4];
#pragma unroll
      for (int r = 0; r < 4; ++r) {
        int d = dt * 16 + 4 * g + r;
        vv[r] = (ctx[dt][r] * fme + Xb[d * 65 + tw * 16 + c]) * invL;
      }
      float4 v; v.x = vv[0]; v.y = vv[1]; v.z = vv[2]; v.w = vv[3];
      *(float4*)(orow + dt * 16 + 4 * g) = v;
    }
  }
}

extern "C" void kernel_launch(void* const* d_in, const int* in_sizes, int n_in,
                              void* d_out, int out_size, void* d_ws, size_t ws_size,
                              hipStream_t stream) {
  const float* enc = (const float*)d_in[0];
  const float* dec = (const float*)d_in[1];
  float* out = (float*)d_out;
  (void)in_sizes; (void)n_in; (void)out_size; (void)ws_size;

  _Float16* encK  = (_Float16*)d_ws;                           // 8 MiB
  _Float16* encVt = (_Float16*)((char*)d_ws + 8388608);        // 8 MiB

  prep_fused<<<1024, 256, 0, stream>>>(enc, encK, encVt);
  // LDS: K 2x16KB x 2 groups = 64 KB; Xb reuse [256][65] f32 = 66560 B; mlb 1 KB
  luong_main<<<256, 512, 67584, stream>>>(encK, encVt, dec, out);
}